// Round 15
// baseline (232.919 us; speedup 1.0000x reference)
//
#include <hip/hip_runtime.h>
#include <hip/hip_bf16.h>

#define TT    512
#define ISZ   9
#define HH    50
#define NB    8       // batches per block; 2 blocks/CU
#define NWAVE 8       // w0-6: compute (tiles 2w,2w+1; w6 -> tile 12); w7: x stager
#define NTH   (NWAVE * 64)   // 512 threads
#define KDIM  64
// K layout (f16, per batch-column), col stride 128 B, buffers toggle +0x400:
//   k=j      : h_j (j=0..49)
//   k=50+i   : x_i (i=0..8)
//   k=59..63 : pad / dead-write dump (A zero there)
// hbuf: [2][NB=8][KDIM=64] f16 = 2 x 1024 B.
// Each compute wave: 2 tiles on one B-read pair; tile-B accs shuffled to the
// upper 8 batch-lanes (cols 8-15 of the MFMA are dead with NB=8) so all 64
// lanes run exactly one cell update. Bias rides in each MFMA's C-input.

typedef _Float16 f16x8_t __attribute__((ext_vector_type(8)));
typedef float    f32x4_t __attribute__((ext_vector_type(4)));

#define L2E    1.44269504088896340736f
#define TWOL2E 2.88539008177792681472f

// barrier draining ONLY lgkmcnt (ds ops) — vmcnt (x prefetch) stays in flight
#define BAR() asm volatile("s_waitcnt lgkmcnt(0)\n\ts_barrier" ::: "memory")

__device__ __forceinline__ unsigned short f16h(float v) {
  _Float16 b = (_Float16)v;
  return __builtin_bit_cast(unsigned short, b);
}
__device__ __forceinline__ float sg_exp2(float z) { return __builtin_amdgcn_exp2f(z); }
__device__ __forceinline__ float rcp_f(float z)   { return __builtin_amdgcn_rcpf(z); }

__global__ __launch_bounds__(NTH, 4) void lstm_mfma(
    const float* __restrict__ x,
    const float* __restrict__ w_ih,
    const float* __restrict__ w_hh,
    const float* __restrict__ b_ih,
    const float* __restrict__ b_hh,
    const float* __restrict__ fc_w,
    const float* __restrict__ fc_b,
    float* __restrict__ out) {
  __shared__ __align__(16) unsigned short hbuf[2][NB * KDIM];  // 2 x 1024 B
  __shared__ float redbuf[NWAVE][NB];

  const int tid = threadIdx.x;
  const int w   = tid >> 6;          // wave id; w<7 compute, w==7 stager
  const int l   = tid & 63;
  const int lb  = l & 15;            // MFMA column; batch = lb&7
  const int kq  = l >> 4;            // k-quarter 0..3
  const int bsel = lb & 7;           // batch column this lane serves
  const bool upper = (lb >= 8);
  const int b0  = blockIdx.x * NB;
  const bool cw = (w < 7);

  // ---- zero both h buffers
  for (int i = tid; i < (2 * NB * KDIM) / 2; i += NTH)
    reinterpret_cast<unsigned*>(hbuf)[i] = 0u;

  // x-stager mapping (wave 7): e1 = l (0..63), e2 = 64+l (l<8); 72 elements
  const bool sw = (w == 7);
  const int e1 = l, e2 = 64 + l;
  const bool s2 = sw && (l < 8);
  const int b1 = e1 / ISZ, i1 = e1 - b1 * ISZ;
  const int b2 = e2 / ISZ, i2 = e2 - b2 * ISZ;
  const int xwo1 = ((b1 << 7) + ((50 + i1) << 1)) ^ (b1 << 4);
  const int xwo2 = ((b2 << 7) + ((50 + i2) << 1)) ^ (b2 << 4);
  const float* xp1 = x + (size_t)(b0 + b1) * (TT * ISZ) + i1;
  const float* xp2 = x + (size_t)(b0 + (b2 & 7)) * (TT * ISZ) + i2;
  __syncthreads();
  // ---- x(t=0) into buf0
  if (sw) {
    *(unsigned short*)((char*)hbuf[0] + xwo1) = f16h(*xp1);
    if (s2) *(unsigned short*)((char*)hbuf[0] + xwo2) = f16h(*xp2);
  }

  // ---- static A fragments for tiles tA=2w, tB=2w+1 (w6: both = 12), f16,
  // weights pre-scaled: i,f,o rows * -log2e ; g row * 2log2e.  rp = 4j+g.
  const int tA = (w < 6) ? (2 * w)     : 12;
  const int tB = (w < 6) ? (2 * w + 1) : 12;
  f16x8_t afragA[2], afragB[2];
#pragma unroll
  for (int tt = 0; tt < 2; ++tt) {
    const int tile = tt ? tB : tA;
    const int rp   = tile * 16 + lb;
    const int jA_  = rp >> 2;
    const int gA   = rp & 3;
    const int rowA = gA * HH + jA_;
    const bool liveA = cw && (jA_ < HH);
    const float scA = (gA == 2) ? TWOL2E : (-L2E);
#pragma unroll
    for (int ks = 0; ks < 2; ++ks) {
#pragma unroll
      for (int e = 0; e < 8; ++e) {
        const int K = ks * 32 + kq * 8 + e;
        float v = 0.0f;
        if (liveA) {
          if (K < HH)            v = w_hh[rowA * HH + K] * scA;
          else if (K < HH + ISZ) v = w_ih[rowA * ISZ + (K - HH)] * scA;
        }
        if (tt) afragB[ks][e] = (_Float16)v; else afragA[ks][e] = (_Float16)v;
      }
    }
  }

  // ---- per-lane bias C-init (exact f32, pre-scaled) for cells jA, jB
  const int jA = tA * 4 + kq;        // w6: 48..51 (50,51 dead)
  const int jB = tB * 4 + kq;
  const bool liveA0 = cw && (jA < HH);
  const bool liveB0 = cw && (w < 6);   // jB < 48 always when w<6
  f32x4_t biasA = {0.f, 0.f, 0.f, 0.f};
  f32x4_t biasB = {0.f, 0.f, 0.f, 0.f};
#pragma unroll
  for (int r = 0; r < 4; ++r) {
    const float sc = (r == 2) ? TWOL2E : (-L2E);
    if (liveA0) biasA[r] = (b_ih[r * HH + jA] + b_hh[r * HH + jA]) * sc;
    if (liveB0) biasB[r] = (b_ih[r * HH + jB] + b_hh[r * HH + jB]) * sc;
  }

  // ---- loop-invariant LDS byte addresses (buf0-relative; buf1 = +0x400 imm)
  char* const base = (char*)hbuf[0];
  const int swzb = bsel << 4;
  const int rd0 = ((bsel << 7) + 0  + (kq << 4)) ^ swzb;   // k 0..31
  const int rd1 = ((bsel << 7) + 64 + (kq << 4)) ^ swzb;   // k 32..63
  // write slot: lower lanes -> tile A cell (dead j -> k=63); upper -> tile B
  // (w6 upper = duplicate -> dump k=59+kq)
  const int kA = (jA < HH) ? jA : 63;
  const int kB = (w < 6) ? jB : (59 + kq);
  const int ksel = upper ? kB : kA;
  const int woS = (((bsel << 7) + (ksel << 1)) ^ swzb);

  float csc = 0.0f, h0 = 0.0f;       // csc = c * 2*L2E (pre-scaled cell state)
  float xv1 = 0.0f, xv2 = 0.0f;      // stager: x(t+1); prefetch depth 2
  if (sw) { xv1 = xp1[ISZ]; xp1 += 2 * ISZ; }
  if (s2) { xv2 = xp2[ISZ]; xp2 += 2 * ISZ; }

#define STEP(T, CUR, NXT)                                                        \
  if (cw) {                                                                      \
    BAR();                                                                       \
    f16x8_t bb0 = *(const f16x8_t*)(base + rd0 + (CUR));                         \
    f16x8_t bb1 = *(const f16x8_t*)(base + rd1 + (CUR));                         \
    f32x4_t accA = __builtin_amdgcn_mfma_f32_16x16x32_f16(afragA[0], bb0, biasA, 0,0,0); \
    f32x4_t accB = __builtin_amdgcn_mfma_f32_16x16x32_f16(afragB[0], bb0, biasB, 0,0,0); \
    accA = __builtin_amdgcn_mfma_f32_16x16x32_f16(afragA[1], bb1, accA, 0,0,0);  \
    accB = __builtin_amdgcn_mfma_f32_16x16x32_f16(afragB[1], bb1, accB, 0,0,0);  \
    const float s0 = __shfl_xor(accB[0], 8);                                     \
    const float s1 = __shfl_xor(accB[1], 8);                                     \
    const float s2v = __shfl_xor(accB[2], 8);                                    \
    const float s3 = __shfl_xor(accB[3], 8);                                     \
    const float z0 = upper ? s0 : accA[0];                                       \
    const float z1 = upper ? s1 : accA[1];                                       \
    const float z2 = upper ? s2v : accA[2];                                      \
    const float z3 = upper ? s3 : accA[3];                                       \
    const float pi = sg_exp2(z0);       /* e^-zi  */                             \
    const float pf = sg_exp2(z1);       /* e^-zf  */                             \
    const float eg = sg_exp2(z2);       /* e^+2zg */                             \
    const float po = sg_exp2(z3);       /* e^-zo  */                             \
    const float A1 = 1.0f + pi, A2 = 1.0f + eg, A3 = 1.0f + pf;                  \
    const float P  = A1 * A2;                                                    \
    const float R  = rcp_f(P * A3);                                              \
    const float t1 = fmaf(P, csc, (eg - 1.0f) * TWOL2E * A3);                    \
    csc = t1 * R;                       /* csc = 2*L2E*c */                      \
    const float ec = sg_exp2(csc);                                               \
    const float r2 = rcp_f((1.0f + po) * (1.0f + ec));                           \
    h0 = (ec - 1.0f) * r2;                                                       \
    *(unsigned short*)(base + woS + (NXT)) = f16h(h0);                           \
  } else {                                                                       \
    float xn1 = 0.0f, xn2 = 0.0f;                                                \
    if (sw && (T) + 2 < TT) { xn1 = *xp1; if (s2) xn2 = *xp2; }                  \
    if (sw) xp1 += ISZ;                                                          \
    if (s2) xp2 += ISZ;                                                          \
    BAR();                                                                       \
    if (sw && (T) + 1 < TT) {                                                    \
      *(unsigned short*)(base + xwo1 + (NXT)) = f16h(xv1);                       \
      if (s2) *(unsigned short*)(base + xwo2 + (NXT)) = f16h(xv2);               \
    }                                                                            \
    xv1 = xn1; xv2 = xn2;                                                        \
  }

  for (int t2 = 0; t2 < TT; t2 += 2) {
    STEP(t2,     0x000, 0x400);   // read buf0, write buf1
    STEP(t2 + 1, 0x400, 0x000);   // read buf1, write buf0
  }
#undef STEP

  // ---- FC epilogue: out[b] = sum_j h_last[j,b]*fc_w[j] + fc_b
  float p = 0.0f;
  if (cw) {
    if (!upper) { if (jA < HH) p = h0 * fc_w[jA]; }
    else if (w < 6) p = h0 * fc_w[jB];
  }
  p += __shfl_xor(p, 8);
  p += __shfl_xor(p, 16);
  p += __shfl_xor(p, 32);
  if (l < NB) redbuf[w][l] = p;
  __syncthreads();
  if (tid < NB) {
    float a = fc_b[0];
#pragma unroll
    for (int ww = 0; ww < NWAVE; ++ww) a += redbuf[ww][tid];
    out[b0 + tid] = a;
  }
}

extern "C" void kernel_launch(void* const* d_in, const int* in_sizes, int n_in,
                              void* d_out, int out_size, void* d_ws, size_t ws_size,
                              hipStream_t stream) {
  const float* x    = (const float*)d_in[0];
  const float* w_ih = (const float*)d_in[1];
  const float* w_hh = (const float*)d_in[2];
  const float* b_ih = (const float*)d_in[3];
  const float* b_hh = (const float*)d_in[4];
  const float* fc_w = (const float*)d_in[5];
  const float* fc_b = (const float*)d_in[6];
  float* out = (float*)d_out;
  const int Btot = in_sizes[0] / (TT * ISZ);   // 4096
  dim3 grid(Btot / NB), block(NTH);            // 512 blocks -> 2 per CU
  hipLaunchKernelGGL(lstm_mfma, grid, block, 0, stream,
                     x, w_ih, w_hh, b_ih, b_hh, fc_w, fc_b, out);
}

// Round 16
// 183.532 us; speedup vs baseline: 1.2691x; 1.2691x over previous
//
#include <hip/hip_runtime.h>
#include <hip/hip_bf16.h>

#define TT    512
#define ISZ   9
#define HH    50
#define NB    16      // batches per block
#define NWAVE 16      // waves 0-12: one 16-row tile each; waves 13-15: x staging
#define NTH   (NWAVE * 64)   // 1024 threads
#define KDIM  64
// K layout (bf16, per batch-column), buffer stride 128 B, toggle ^0x800:
//   k=j      : h_j bf16 (j=0..49)
//   k=50+i   : x_i bf16 (i=0..8)
//   k=59..63 : zero pad (A zero there; dead cells j=50,51 dump to k=59,60)
// Bias is carried in the MFMA C-input (exact f32, pre-scaled); first MFMA
// seeds from C=bias regs (no acc-init movs).

typedef __bf16 bf16x8_t __attribute__((ext_vector_type(8)));
typedef float  f32x4_t  __attribute__((ext_vector_type(4)));

#define L2E  1.44269504088896340736f

// barrier draining ONLY lgkmcnt (ds ops) — vmcnt (x prefetch) stays in flight
#define BAR() asm volatile("s_waitcnt lgkmcnt(0)\n\ts_barrier" ::: "memory")

__device__ __forceinline__ unsigned short bf16_rne(float f) {
  unsigned u = __builtin_bit_cast(unsigned, f);
  unsigned r = (u + 0x7FFFu + ((u >> 16) & 1u)) >> 16;
  return (unsigned short)r;
}
__device__ __forceinline__ unsigned short bf16h(float v) {
  __bf16 b = (__bf16)v;
  return __builtin_bit_cast(unsigned short, b);
}
__device__ __forceinline__ float sg_exp2(float z) { return __builtin_amdgcn_exp2f(z); }
__device__ __forceinline__ float rcp_f(float z)   { return __builtin_amdgcn_rcpf(z); }

__global__ __launch_bounds__(NTH, 1) void lstm_mfma(
    const float* __restrict__ x,
    const float* __restrict__ w_ih,
    const float* __restrict__ w_hh,
    const float* __restrict__ b_ih,
    const float* __restrict__ b_hh,
    const float* __restrict__ fc_w,
    const float* __restrict__ fc_b,
    float* __restrict__ out) {
  __shared__ __align__(16) unsigned short hbuf[2][NB * KDIM];  // 2 x 2048 B
  __shared__ float redbuf[NWAVE][NB];

  const int tid = threadIdx.x;
  const int w   = tid >> 6;          // wave id; w<13 = compute (tile w), w>=13 = x-stager
  const int l   = tid & 63;
  const int lb  = l & 15;            // batch column
  const int kq  = l >> 4;            // k-quarter 0..3 (16B chunks within 64B half)
  const int b0  = blockIdx.x * NB;
  const bool cw = (w < 13);

  // ---- zero both h buffers
  for (int i = tid; i < (2 * NB * KDIM) / 2; i += NTH)
    reinterpret_cast<unsigned*>(hbuf)[i] = 0u;

  // x-stager mapping (waves 13-15: 192 lanes, 144 active)
  const int xt = tid - 13 * 64;
  const bool xact = (xt >= 0 && xt < NB * ISZ);
  const int xb = xact ? (xt / ISZ) : 0;
  const int xi = xact ? (xt - xb * ISZ) : 0;
  __syncthreads();
  // ---- x(t=0) into buf0
  if (xact) {
    float xv = x[(size_t)(b0 + xb) * (TT * ISZ) + xi];
    *(unsigned short*)((char*)hbuf[0] + (((xb << 7) + ((50 + xi) << 1)) ^ ((xb & 7) << 4))) = bf16h(xv);
  }

  // ---- static A fragment (tile w), weights pre-scaled:
  //   i,f,o rows: * -log2e ; g row: * 2log2e
  // Row permutation rp = 4j+g so lane's 4 acc regs = (i,f,g,o) of one j.
  // Lane holds A[row = rp][K = 32*ks + 8*kq + e].
  bf16x8_t afrag[2];
  {
    const int rp   = w * 16 + lb;
    const int jA   = rp >> 2;
    const int gA   = rp & 3;
    const int rowA = gA * HH + jA;
    const bool liveA = cw && (jA < HH);
    const float scA = (gA == 2) ? (2.0f * L2E) : (-L2E);
#pragma unroll
    for (int ks = 0; ks < 2; ++ks) {
#pragma unroll
      for (int e = 0; e < 8; ++e) {
        const int K = ks * 32 + kq * 8 + e;
        unsigned short bits = 0;
        if (liveA) {
          if (K < HH)                 bits = bf16_rne(w_hh[rowA * HH + K] * scA);
          else if (K < HH + ISZ)      bits = bf16_rne(w_ih[rowA * ISZ + (K - HH)] * scA);
        }
        afrag[ks][e] = __builtin_bit_cast(__bf16, bits);
      }
    }
  }

  // ---- per-lane bias C-init (exact f32, pre-scaled) for cell (j0, lb)
  const int j0 = w * 4 + kq;          // tile 12: kq 2,3 -> dead j 50,51
  const bool live0 = cw && (j0 < HH);
  f32x4_t bias0 = {0.f, 0.f, 0.f, 0.f};
  if (live0) {
#pragma unroll
    for (int r = 0; r < 4; ++r) {
      const float sc = (r == 2) ? (2.0f * L2E) : (-L2E);
      bias0[r] = (b_ih[r * HH + j0] + b_hh[r * HH + j0]) * sc;
    }
  }

  // ---- loop-invariant LDS byte addresses (buf0-relative; buf1 = +0x800 imm)
  char* const base = (char*)hbuf[0];
  const int swzb = (lb & 7) << 4;
  const int rd0 = ((lb << 7) + 0  + (kq << 4)) ^ swzb;
  const int rd1 = ((lb << 7) + 64 + (kq << 4)) ^ swzb;
  const int j0c = (j0 < HH) ? j0 : (j0 + 9);      // dead j 50,51 -> pad cols 59,60
  const int wo0 = (((lb << 7) + (j0c << 1)) ^ swzb);
  const int xwo = (((xb << 7) + ((50 + xi) << 1)) ^ ((xb & 7) << 4));

  const float* xp = x + (size_t)(b0 + xb) * (TT * ISZ) + xi;
  float csc = 0.0f, h0 = 0.0f;       // csc = c * 2*L2E (pre-scaled cell state)
  float xv_n = 0.0f;                 // x(t+1); prefetch depth 2
  if (xact) xv_n = xp[ISZ];
  xp += 2 * ISZ;

#define STEP(T, ROFF, WOFF)                                                      \
  if (cw) {                                                                      \
    BAR();                                                                       \
    bf16x8_t bb0 = *(const bf16x8_t*)(base + rd0 + (ROFF));                      \
    bf16x8_t bb1 = *(const bf16x8_t*)(base + rd1 + (ROFF));                      \
    f32x4_t acc;                                                                 \
    acc = __builtin_amdgcn_mfma_f32_16x16x32_bf16(afrag[0], bb0, bias0, 0,0,0);  \
    acc = __builtin_amdgcn_mfma_f32_16x16x32_bf16(afrag[1], bb1, acc,   0,0,0);  \
    const float pi = sg_exp2(acc[0]);   /* e^-zi  */                             \
    const float pf = sg_exp2(acc[1]);   /* e^-zf  */                             \
    const float eg = sg_exp2(acc[2]);   /* e^+2zg */                             \
    const float po = sg_exp2(acc[3]);   /* e^-zo  */                             \
    const float r1 = rcp_f((1.0f + pi) * (1.0f + eg));                           \
    const float fv = rcp_f(1.0f + pf);                                           \
    const float ig2 = (eg - 1.0f) * r1 * (2.0f * L2E);                           \
    csc = fmaf(fv, csc, ig2);           /* csc = 2*L2E*c */                      \
    const float ec = sg_exp2(csc);                                               \
    const float r2 = rcp_f((1.0f + po) * (1.0f + ec));                           \
    h0 = (ec - 1.0f) * r2;                                                       \
    *(unsigned short*)(base + wo0 + (WOFF)) = bf16h(h0);                         \
  } else {                                                                       \
    float xv_new = 0.0f;                                                         \
    if (xact && (T) + 2 < TT) xv_new = *xp;                                      \
    xp += ISZ;                                                                   \
    BAR();                                                                       \
    if (xact && (T) + 1 < TT) *(unsigned short*)(base + xwo + (WOFF)) = bf16h(xv_n); \
    xv_n = xv_new;                                                               \
  }

  for (int t2 = 0; t2 < TT; t2 += 2) {
    STEP(t2,     0x000, 0x800);   // read buf0, write buf1
    STEP(t2 + 1, 0x800, 0x000);   // read buf1, write buf0
  }
#undef STEP

  // ---- FC epilogue: out[b] = sum_j h_last[j,b]*fc_w[j] + fc_b
  float p = live0 ? h0 * fc_w[j0] : 0.0f;
  p += __shfl_xor(p, 16);
  p += __shfl_xor(p, 32);
  if (l < NB) redbuf[w][l] = p;
  __syncthreads();
  if (tid < NB) {
    float a = fc_b[0];
#pragma unroll
    for (int ww = 0; ww < NWAVE; ++ww) a += redbuf[ww][tid];
    out[b0 + tid] = a;
  }
}

extern "C" void kernel_launch(void* const* d_in, const int* in_sizes, int n_in,
                              void* d_out, int out_size, void* d_ws, size_t ws_size,
                              hipStream_t stream) {
  const float* x    = (const float*)d_in[0];
  const float* w_ih = (const float*)d_in[1];
  const float* w_hh = (const float*)d_in[2];
  const float* b_ih = (const float*)d_in[3];
  const float* b_hh = (const float*)d_in[4];
  const float* fc_w = (const float*)d_in[5];
  const float* fc_b = (const float*)d_in[6];
  float* out = (float*)d_out;
  const int Btot = in_sizes[0] / (TT * ISZ);   // 4096
  dim3 grid(Btot / NB), block(NTH);
  hipLaunchKernelGGL(lstm_mfma, grid, block, 0, stream,
                     x, w_ih, w_hh, b_ih, b_hh, fc_w, fc_b, out);
}